// Round 11
// baseline (195.639 us; speedup 1.0000x reference)
//
#include <hip/hip_runtime.h>

#define KK 12
#define LL 4096
#define DD 128
#define NN 16
#define RR 8
#define NC 256             // sub-chunks (two per block)
#define LCS 16             // sub-chunk length
#define LB 32              // block l-tile
#define XST 140            // x-tile / ybuf LDS stride (4-way GEMM reads)
#define SDST 44            // x_dbl LDS row stride (floats)

__device__ __forceinline__ int pos_of(int k, int l) {
    int o = k >> 1;
    int le = (k & 1) ? (4095 - l) : l;
    int t1 = le >> 8, t2 = (le >> 4) & 15, t3 = le & 15;
    switch (o) {
        case 0:  return (t1 << 8) | (t2 << 4) | t3;
        case 1:  return (t1 << 8) | (t3 << 4) | t2;
        case 2:  return (t3 << 8) | (t2 << 4) | t1;
        case 3:  return (t2 << 8) | (t3 << 4) | t1;
        case 4:  return (t2 << 8) | (t1 << 4) | t3;
        default: return (t3 << 8) | (t1 << 4) | t2;
    }
}

// ---- bf16 pack/unpack (RNE) ----
__device__ __forceinline__ unsigned pk_bf2(float a, float b) {
    unsigned ua = __float_as_uint(a); ua = (ua + 0x7FFF + ((ua >> 16) & 1)) >> 16;
    unsigned ub = __float_as_uint(b); ub = (ub + 0x7FFF + ((ub >> 16) & 1)) >> 16;
    return ua | (ub << 16);
}
__device__ __forceinline__ float lo_bf(unsigned u) { return __uint_as_float(u << 16); }
__device__ __forceinline__ float hi_bf(unsigned u) { return __uint_as_float(u & 0xFFFF0000u); }

__device__ __forceinline__ float delta_row_z(const float* sdbl, int l,
                                             float4 w0, float4 w1, float bz) {
    const float4* dr = (const float4*)(sdbl + l * SDST);
    float4 r0 = dr[0], r1 = dr[1];
    return bz + w0.x * r0.x + w0.y * r0.y + w0.z * r0.z + w0.w * r0.w
              + w1.x * r1.x + w1.y * r1.y + w1.z * r1.z + w1.w * r1.w;
}

// Load -exp(A_logs[k][d][0..15]); check A[n] == (n+1)*A[0] structure.
__device__ __forceinline__ bool load_A16(const float* __restrict__ A_logs,
                                         int k, int d, float* A16) {
    const float4* ap = (const float4*)(A_logs + (size_t)(k * DD + d) * NN);
    #pragma unroll
    for (int q = 0; q < 4; q++) {
        float4 a4 = ap[q];
        A16[4*q+0] = -__expf(a4.x); A16[4*q+1] = -__expf(a4.y);
        A16[4*q+2] = -__expf(a4.z); A16[4*q+3] = -__expf(a4.w);
    }
    bool s = true;
    #pragma unroll
    for (int j = 1; j < 16; j++) {
        float m = (float)(j + 1);
        s = s && (fabsf(A16[j] - m * A16[0]) <= 1e-4f * m * fabsf(A16[0]));
    }
    return s;
}

// e[j] = q^(j+1), log-depth tree (depth ~4 vs 15 serial muls)
__device__ __forceinline__ void e16_tree(float q, float* e) {
    e[0] = q;
    float q2 = q * q;
    e[1] = q2; e[2] = q2 * q; e[3] = q2 * q2;
    e[4] = e[3] * q;   e[5] = e[3] * q2;  e[6] = e[3] * e[2];  e[7] = e[3] * e[3];
    e[8] = e[7] * q;   e[9] = e[7] * q2;  e[10] = e[7] * e[2]; e[11] = e[7] * e[3];
    e[12] = e[7] * e[4]; e[13] = e[7] * e[5]; e[14] = e[7] * e[6]; e[15] = e[7] * e[7];
}

template<bool S>
__device__ __forceinline__ void e16_from(float v, const float* A16, float* e) {
    if (S) {
        e16_tree(__expf(v * A16[0]), e);
    } else {
        #pragma unroll
        for (int j = 0; j < 16; j++) e[j] = __expf(v * A16[j]);
    }
}

// ---------------------------------------------------------------------------
// K1 scan body. Thread = (d, l-half): all 16 states, 16 serial steps.
// Stores inclusive prefix Dsum per (l,d) for the parallel correction pass.
// ---------------------------------------------------------------------------
template<bool S>
__device__ __forceinline__ void scanA_body(
    float* xs, const float* sdbl, int k, int cc, int lbase, int d,
    const float* A16, float4 w0, float4 w1, float bz, float Dval,
    unsigned* __restrict__ S_b, float* __restrict__ dtsum,
    float* __restrict__ dslp)
{
    float h[16];
    #pragma unroll
    for (int n = 0; n < 16; n++) h[n] = 0.0f;
    float dsum = 0.0f;

    #pragma unroll 4
    for (int i = 0; i < LCS; i++) {
        int l = lbase + i;
        float z = delta_row_z(sdbl, l, w0, w1, bz);
        float E = __expf(-fabsf(z));
        float dt = fmaxf(z, 0.0f) + __logf(1.0f + E);
        float u = xs[l * XST + d];
        dsum += dt;
        dslp[i] = dsum;                      // inclusive prefix
        float tu = dt * u;
        float e[16];
        e16_from<S>(dt, A16, e);
        const float4* bp = (const float4*)(&sdbl[l * SDST + 8]);
        float4 b0 = bp[0], b1 = bp[1], b2 = bp[2], b3 = bp[3];
        const float4* cp = (const float4*)(&sdbl[l * SDST + 24]);
        float4 c0 = cp[0], c1 = cp[1], c2 = cp[2], c3 = cp[3];
        h[0]  = e[0]  * h[0]  + tu * b0.x;  h[1]  = e[1]  * h[1]  + tu * b0.y;
        h[2]  = e[2]  * h[2]  + tu * b0.z;  h[3]  = e[3]  * h[3]  + tu * b0.w;
        h[4]  = e[4]  * h[4]  + tu * b1.x;  h[5]  = e[5]  * h[5]  + tu * b1.y;
        h[6]  = e[6]  * h[6]  + tu * b1.z;  h[7]  = e[7]  * h[7]  + tu * b1.w;
        h[8]  = e[8]  * h[8]  + tu * b2.x;  h[9]  = e[9]  * h[9]  + tu * b2.y;
        h[10] = e[10] * h[10] + tu * b2.z;  h[11] = e[11] * h[11] + tu * b2.w;
        h[12] = e[12] * h[12] + tu * b3.x;  h[13] = e[13] * h[13] + tu * b3.y;
        h[14] = e[14] * h[14] + tu * b3.z;  h[15] = e[15] * h[15] + tu * b3.w;
        float y = h[0]*c0.x + h[1]*c0.y + h[2]*c0.z + h[3]*c0.w
                + h[4]*c1.x + h[5]*c1.y + h[6]*c1.z + h[7]*c1.w
                + h[8]*c2.x + h[9]*c2.y + h[10]*c2.z + h[11]*c2.w
                + h[12]*c3.x + h[13]*c3.y + h[14]*c3.z + h[15]*c3.w;
        xs[l * XST + d] = y + Dval * u;
    }

    // packed bf16 chunk end-state
    size_t b8 = ((size_t)(k * NC + cc) * DD + d) * 8;
    uint4 p0, p1;
    p0.x = pk_bf2(h[0],  h[1]);  p0.y = pk_bf2(h[2],  h[3]);
    p0.z = pk_bf2(h[4],  h[5]);  p0.w = pk_bf2(h[6],  h[7]);
    p1.x = pk_bf2(h[8],  h[9]);  p1.y = pk_bf2(h[10], h[11]);
    p1.z = pk_bf2(h[12], h[13]); p1.w = pk_bf2(h[14], h[15]);
    *(uint4*)(S_b + b8)     = p0;
    *(uint4*)(S_b + b8 + 4) = p1;
    dtsum[(k * NC + cc) * DD + d] = dsum;
}

// ---------------------------------------------------------------------------
// K1: proj GEMM + phase A local scan. Block = (k, 32-l tile), 256 threads.
// ---------------------------------------------------------------------------
__global__ __launch_bounds__(256, 4) void k1_proj_scanA(
    const float* __restrict__ x, const float* __restrict__ Wp,
    const float* __restrict__ Wdt, const float* __restrict__ bias,
    const float* __restrict__ A_logs, const float* __restrict__ Ds,
    unsigned* __restrict__ S_b, float* __restrict__ dtsum,
    float* __restrict__ oy, float* __restrict__ csp,
    float* __restrict__ dsl)
{
    const int blk = blockIdx.x;
    const int k = blk >> 7;
    const int c = blk & 127;
    const int l0 = c * LB;
    const int t = threadIdx.x;

    __shared__ __align__(16) float xs[LB * XST];    // x-tile [l][d]; y overwrites
    __shared__ __align__(16) float sdbl[LB * SDST]; // x_dbl [l][c]
    __shared__ int pos_s[LB];

    if (t < LB) pos_s[t] = pos_of(k, l0 + t);
    __syncthreads();

    // ---- stage x tile (coalesced) ----
    {
        int lane32 = t & 31, rowi = t >> 5;
        #pragma unroll
        for (int p = 0; p < 4; p++) {
            int l = p * 8 + rowi;
            float4 v = *(const float4*)(x + (size_t)pos_s[l] * DD + lane32 * 4);
            *(float4*)(&xs[l * XST + lane32 * 4]) = v;
        }
    }
    __syncthreads();

    // ---- projection GEMM: group cg (of 8) computes 5 of 40 channels ----
    {
        int l = t & 31, cg = t >> 5;
        float acc[5];
        #pragma unroll
        for (int j = 0; j < 5; j++) acc[j] = 0.0f;
        const float* wk = Wp + (size_t)(k * 40 + cg * 5) * DD;
        for (int d4 = 0; d4 < DD; d4 += 4) {
            float4 xv = *(const float4*)(&xs[l * XST + d4]);
            #pragma unroll
            for (int j = 0; j < 5; j++) {
                const float* w = wk + j * DD + d4;   // wave-uniform -> s_load
                acc[j] += xv.x * w[0] + xv.y * w[1] + xv.z * w[2] + xv.w * w[3];
            }
        }
        #pragma unroll
        for (int j = 0; j < 5; j++) sdbl[l * SDST + cg * 5 + j] = acc[j];
    }
    __syncthreads();

    // ---- spill C columns only (32 l x 16 n) for K3 ----
    {
        float4* g4 = (float4*)(csp + (size_t)blk * 512);
        for (int idx = t; idx < 128; idx += 256) {
            int l = idx >> 2, q = idx & 3;
            g4[idx] = *(const float4*)(&sdbl[l * SDST + 24 + q * 4]);
        }
    }

    // ---- phase A scan: thread = (d, l-half) ----
    const int d = t & 127, half = t >> 7;
    const int cc = 2 * c + half, lbase = half * LCS;
    float A16[16];
    bool structured = load_A16(A_logs, k, d, A16);
    const float4* wp4 = (const float4*)(Wdt + (size_t)(k * DD + d) * RR);
    const float4 w0 = wp4[0], w1 = wp4[1];
    const float bz = bias[k * DD + d];
    const float Dval = Ds[k * DD + d];
    float* dslp = dsl + ((size_t)(k * DD + d)) * LL + l0 + lbase;

    if (structured)
        scanA_body<true>(xs, sdbl, k, cc, lbase, d, A16, w0, w1, bz, Dval,
                         S_b, dtsum, dslp);
    else
        scanA_body<false>(xs, sdbl, k, cc, lbase, d, A16, w0, w1, bz, Dval,
                          S_b, dtsum, dslp);

    // ---- transposed y store (self-written slots only; no barrier) ----
    {
        float* base = oy + ((size_t)(k * DD + d)) * LL + l0 + lbase;
        #pragma unroll
        for (int p = 0; p < 4; p++) {
            int j = p * 4;
            float4 v = make_float4(xs[(lbase + j + 0) * XST + d],
                                   xs[(lbase + j + 1) * XST + d],
                                   xs[(lbase + j + 2) * XST + d],
                                   xs[(lbase + j + 3) * XST + d]);
            *(float4*)(base + j) = v;
        }
    }
}

// ---------------------------------------------------------------------------
// K2: sequential combine across 256 sub-chunks; thread owns an n-pair so the
// packed bf16 uint is single-owner. S_b <- true h0, in place.
// ---------------------------------------------------------------------------
__global__ __launch_bounds__(256) void k2_combine(
    unsigned* __restrict__ S_b, const float* __restrict__ dtsum,
    const float* __restrict__ A_logs)
{
    int tid = blockIdx.x * 256 + threadIdx.x;   // k*1024 + d*8 + j(pair)
    int kk = tid >> 10, rem = tid & 1023, dd2 = rem >> 3, j = rem & 7;
    const float* ap = A_logs + ((size_t)kk * DD + dd2) * NN + 2 * j;
    float A0 = -__expf(ap[0]), A1 = -__expf(ap[1]);
    float h0 = 0.0f, h1 = 0.0f;
    #pragma unroll 8
    for (int c2 = 0; c2 < NC; c2++) {
        size_t b8 = ((size_t)(kk * NC + c2) * DD + dd2) * 8 + j;
        unsigned u = S_b[b8];
        float dsv = dtsum[(kk * NC + c2) * DD + dd2];
        float s0 = lo_bf(u), s1 = hi_bf(u);
        S_b[b8] = pk_bf2(h0, h1);
        h0 = s0 + __expf(dsv * A0) * h0;
        h1 = s1 + __expf(dsv * A1) * h1;
    }
}

// ---------------------------------------------------------------------------
// K3: correction, fully parallel (no serial deps, no dt recompute):
// y_corr(l) = sum_n C[n,l] * exp(Dsum_l * A[n]) * h0[n], Dsum loaded from dsl.
// ---------------------------------------------------------------------------
template<bool S>
__device__ __forceinline__ void corr_body(
    float* ybuf, const float* csp_s, const float* dslp, int lbase, int d,
    const float* A16, const float* g)
{
    #pragma unroll 4
    for (int i = 0; i < LCS; i++) {
        int l = lbase + i;
        float Dsum = dslp[i];
        float e[16];
        e16_from<S>(Dsum, A16, e);
        const float4* cp = (const float4*)(&csp_s[l * 16]);
        float4 c0 = cp[0], c1 = cp[1], c2 = cp[2], c3 = cp[3];
        float y = e[0]*g[0]*c0.x + e[1]*g[1]*c0.y + e[2]*g[2]*c0.z + e[3]*g[3]*c0.w
                + e[4]*g[4]*c1.x + e[5]*g[5]*c1.y + e[6]*g[6]*c1.z + e[7]*g[7]*c1.w
                + e[8]*g[8]*c2.x + e[9]*g[9]*c2.y + e[10]*g[10]*c2.z + e[11]*g[11]*c2.w
                + e[12]*g[12]*c3.x + e[13]*g[13]*c3.y + e[14]*g[14]*c3.z + e[15]*g[15]*c3.w;
        ybuf[l * XST + d] = y;
    }
}

__global__ __launch_bounds__(256, 4) void k3_corr(
    const float* __restrict__ A_logs, const unsigned* __restrict__ S_b,
    const float* __restrict__ csp, const float* __restrict__ dsl,
    float* __restrict__ oy)
{
    const int blk = blockIdx.x;
    const int k = blk >> 7;
    const int c = blk & 127;
    const int l0 = c * LB;
    const int t = threadIdx.x;

    __shared__ __align__(16) float csp_s[LB * 16];
    __shared__ __align__(16) float ybuf[LB * XST];
    {
        const float4* g4 = (const float4*)(csp + (size_t)blk * 512);
        float4* s4 = (float4*)csp_s;
        for (int idx = t; idx < 128; idx += 256) s4[idx] = g4[idx];
    }
    __syncthreads();

    const int d = t & 127, half = t >> 7;
    const int cc = 2 * c + half, lbase = half * LCS;
    float A16[16];
    bool structured = load_A16(A_logs, k, d, A16);
    const float* dslp = dsl + ((size_t)(k * DD + d)) * LL + l0 + lbase;

    float g[16];
    {
        const uint4* hp = (const uint4*)(S_b + ((size_t)(k * NC + cc) * DD + d) * 8);
        uint4 a = hp[0], b = hp[1];
        g[0]  = lo_bf(a.x); g[1]  = hi_bf(a.x); g[2]  = lo_bf(a.y); g[3]  = hi_bf(a.y);
        g[4]  = lo_bf(a.z); g[5]  = hi_bf(a.z); g[6]  = lo_bf(a.w); g[7]  = hi_bf(a.w);
        g[8]  = lo_bf(b.x); g[9]  = hi_bf(b.x); g[10] = lo_bf(b.y); g[11] = hi_bf(b.y);
        g[12] = lo_bf(b.z); g[13] = hi_bf(b.z); g[14] = lo_bf(b.w); g[15] = hi_bf(b.w);
    }

    if (structured)
        corr_body<true>(ybuf, csp_s, dslp, lbase, d, A16, g);
    else
        corr_body<false>(ybuf, csp_s, dslp, lbase, d, A16, g);

    // ---- transposed RMW of oy tile (self-written slots only) ----
    {
        float* base = oy + ((size_t)(k * DD + d)) * LL + l0 + lbase;
        #pragma unroll
        for (int p = 0; p < 4; p++) {
            int j = p * 4;
            float4 v = *(float4*)(base + j);
            v.x += ybuf[(lbase + j + 0) * XST + d];
            v.y += ybuf[(lbase + j + 1) * XST + d];
            v.z += ybuf[(lbase + j + 2) * XST + d];
            v.w += ybuf[(lbase + j + 3) * XST + d];
            *(float4*)(base + j) = v;
        }
    }
}

// ---------------------------------------------------------------------------
// K4: restore + merge (reference's (D,L)-flat reshape semantics).
// ---------------------------------------------------------------------------
__global__ __launch_bounds__(256) void k4_merge(
    const float* __restrict__ out_y, const float* __restrict__ mw,
    const float* __restrict__ mb, float* __restrict__ out)
{
    int idx = blockIdx.x * 256 + threadIdx.x;
    int dd = idx & 127;
    int p = idx >> 7;
    int i3 = p & 15, i2 = (p >> 4) & 15, i1 = (p >> 8) & 15;

    float accv = mb[0];
    #pragma unroll
    for (int k = 0; k < 12; k++) {
        int a1 = i1, a2 = i2, a3 = i3;
        if (k & 1) { a1 = 15 - i1; a2 = 15 - i2; a3 = 15 - i3; }
        int j1, j2, j3;
        switch (k >> 1) {
            case 0:  j1 = a1; j2 = a2; j3 = a3; break;
            case 1:  j1 = a1; j2 = a3; j3 = a2; break;
            case 2:  j1 = a3; j2 = a2; j3 = a1; break;
            case 3:  j1 = a3; j2 = a1; j3 = a2; break;
            case 4:  j1 = a2; j2 = a1; j3 = a3; break;
            default: j1 = a2; j2 = a3; j3 = a1; break;
        }
        int jb = (j1 << 8) | (j2 << 4) | j3;
        accv += mw[k] * out_y[(size_t)k * (DD * LL) + (jb >> 5) * LL
                              + ((jb & 31) << 7) + dd];
    }
    out[idx] = accv;
}

extern "C" void kernel_launch(void* const* d_in, const int* in_sizes, int n_in,
                              void* d_out, int out_size, void* d_ws, size_t ws_size,
                              hipStream_t stream) {
    const float* x      = (const float*)d_in[0];
    const float* Wp     = (const float*)d_in[1];
    const float* Wdt    = (const float*)d_in[2];
    const float* bias   = (const float*)d_in[3];
    const float* A_logs = (const float*)d_in[4];
    const float* Ds     = (const float*)d_in[5];
    const float* mw     = (const float*)d_in[6];
    const float* mb     = (const float*)d_in[7];
    float* out = (float*)d_out;

    // workspace: 67.6 MB total
    unsigned* S_b = (unsigned*)d_ws;                    // K*NC*D*8 uints = 3145728
    float* dts  = (float*)(S_b + (size_t)KK * NC * DD * 8); // K*NC*D    =  393216
    float* oy   = dts + (size_t)KK * NC * DD;           // K*D*L       = 6291456
    float* csp  = oy + (size_t)KK * DD * LL;            // 1536*512    =  786432
    float* dsl  = csp + (size_t)KK * 128 * 512;         // K*D*L       = 6291456

    k1_proj_scanA<<<dim3(KK * 128), dim3(256), 0, stream>>>(
        x, Wp, Wdt, bias, A_logs, Ds, S_b, dts, oy, csp, dsl);
    k2_combine<<<dim3(KK * DD * 8 / 256), dim3(256), 0, stream>>>(S_b, dts, A_logs);
    k3_corr<<<dim3(KK * 128), dim3(256), 0, stream>>>(A_logs, S_b, csp, dsl, oy);
    k4_merge<<<dim3(LL * DD / 256), dim3(256), 0, stream>>>(oy, mw, mb, out);
}

// Round 12
// 171.550 us; speedup vs baseline: 1.1404x; 1.1404x over previous
//
#include <hip/hip_runtime.h>

#define KK 12
#define LL 4096
#define DD 128
#define NN 16
#define RR 8
#define NC 256             // sub-chunks (two per block)
#define LCS 16             // sub-chunk length
#define LB 32              // block l-tile
#define XST 140            // x-tile / ybuf LDS stride (4-way GEMM reads)
#define SDST 44            // x_dbl LDS row stride (floats)

__device__ __forceinline__ int pos_of(int k, int l) {
    int o = k >> 1;
    int le = (k & 1) ? (4095 - l) : l;
    int t1 = le >> 8, t2 = (le >> 4) & 15, t3 = le & 15;
    switch (o) {
        case 0:  return (t1 << 8) | (t2 << 4) | t3;
        case 1:  return (t1 << 8) | (t3 << 4) | t2;
        case 2:  return (t3 << 8) | (t2 << 4) | t1;
        case 3:  return (t2 << 8) | (t3 << 4) | t1;
        case 4:  return (t2 << 8) | (t1 << 4) | t3;
        default: return (t3 << 8) | (t1 << 4) | t2;
    }
}

// ---- bf16 pack/unpack (RNE) ----
__device__ __forceinline__ unsigned pk_bf2(float a, float b) {
    unsigned ua = __float_as_uint(a); ua = (ua + 0x7FFF + ((ua >> 16) & 1)) >> 16;
    unsigned ub = __float_as_uint(b); ub = (ub + 0x7FFF + ((ub >> 16) & 1)) >> 16;
    return ua | (ub << 16);
}
__device__ __forceinline__ float lo_bf(unsigned u) { return __uint_as_float(u << 16); }
__device__ __forceinline__ float hi_bf(unsigned u) { return __uint_as_float(u & 0xFFFF0000u); }

__device__ __forceinline__ float delta_row_z(const float* sdbl, int l,
                                             float4 w0, float4 w1, float bz) {
    const float4* dr = (const float4*)(sdbl + l * SDST);
    float4 r0 = dr[0], r1 = dr[1];
    return bz + w0.x * r0.x + w0.y * r0.y + w0.z * r0.z + w0.w * r0.w
              + w1.x * r1.x + w1.y * r1.y + w1.z * r1.z + w1.w * r1.w;
}

// Load -exp(A_logs[k][d][0..15]); check A[n] == (n+1)*A[0] structure.
__device__ __forceinline__ bool load_A16(const float* __restrict__ A_logs,
                                         int k, int d, float* A16) {
    const float4* ap = (const float4*)(A_logs + (size_t)(k * DD + d) * NN);
    #pragma unroll
    for (int q = 0; q < 4; q++) {
        float4 a4 = ap[q];
        A16[4*q+0] = -__expf(a4.x); A16[4*q+1] = -__expf(a4.y);
        A16[4*q+2] = -__expf(a4.z); A16[4*q+3] = -__expf(a4.w);
    }
    bool s = true;
    #pragma unroll
    for (int j = 1; j < 16; j++) {
        float m = (float)(j + 1);
        s = s && (fabsf(A16[j] - m * A16[0]) <= 1e-4f * m * fabsf(A16[0]));
    }
    return s;
}

// e[j] = q^(j+1), log-depth tree (depth ~4 vs 15 serial muls)
__device__ __forceinline__ void e16_tree(float q, float* e) {
    e[0] = q;
    float q2 = q * q;
    e[1] = q2; e[2] = q2 * q; e[3] = q2 * q2;
    e[4] = e[3] * q;   e[5] = e[3] * q2;  e[6] = e[3] * e[2];  e[7] = e[3] * e[3];
    e[8] = e[7] * q;   e[9] = e[7] * q2;  e[10] = e[7] * e[2]; e[11] = e[7] * e[3];
    e[12] = e[7] * e[4]; e[13] = e[7] * e[5]; e[14] = e[7] * e[6]; e[15] = e[7] * e[7];
}

template<bool S>
__device__ __forceinline__ void e16_from(float v, const float* A16, float* e) {
    if (S) {
        e16_tree(__expf(v * A16[0]), e);
    } else {
        #pragma unroll
        for (int j = 0; j < 16; j++) e[j] = __expf(v * A16[j]);
    }
}

// ---------------------------------------------------------------------------
// K1 scan body. Thread = (d, l-half): all 16 states, 16 serial steps.
// Stores inclusive prefix Dsum to dsl[k][l][d] (wave-coalesced: lanes = d).
// ---------------------------------------------------------------------------
template<bool S>
__device__ __forceinline__ void scanA_body(
    float* xs, const float* sdbl, int k, int cc, int lbase, int d,
    const float* A16, float4 w0, float4 w1, float bz, float Dval,
    unsigned* __restrict__ S_b, float* __restrict__ dtsum,
    float* __restrict__ dslp)   // dslp = &dsl[(k*LL + l0 + lbase)*DD + d]
{
    float h[16];
    #pragma unroll
    for (int n = 0; n < 16; n++) h[n] = 0.0f;
    float dsum = 0.0f;

    #pragma unroll 4
    for (int i = 0; i < LCS; i++) {
        int l = lbase + i;
        float z = delta_row_z(sdbl, l, w0, w1, bz);
        float E = __expf(-fabsf(z));
        float dt = fmaxf(z, 0.0f) + __logf(1.0f + E);
        float u = xs[l * XST + d];
        dsum += dt;
        dslp[(size_t)i * DD] = dsum;         // coalesced 256B wave store
        float tu = dt * u;
        float e[16];
        e16_from<S>(dt, A16, e);
        const float4* bp = (const float4*)(&sdbl[l * SDST + 8]);
        float4 b0 = bp[0], b1 = bp[1], b2 = bp[2], b3 = bp[3];
        const float4* cp = (const float4*)(&sdbl[l * SDST + 24]);
        float4 c0 = cp[0], c1 = cp[1], c2 = cp[2], c3 = cp[3];
        h[0]  = e[0]  * h[0]  + tu * b0.x;  h[1]  = e[1]  * h[1]  + tu * b0.y;
        h[2]  = e[2]  * h[2]  + tu * b0.z;  h[3]  = e[3]  * h[3]  + tu * b0.w;
        h[4]  = e[4]  * h[4]  + tu * b1.x;  h[5]  = e[5]  * h[5]  + tu * b1.y;
        h[6]  = e[6]  * h[6]  + tu * b1.z;  h[7]  = e[7]  * h[7]  + tu * b1.w;
        h[8]  = e[8]  * h[8]  + tu * b2.x;  h[9]  = e[9]  * h[9]  + tu * b2.y;
        h[10] = e[10] * h[10] + tu * b2.z;  h[11] = e[11] * h[11] + tu * b2.w;
        h[12] = e[12] * h[12] + tu * b3.x;  h[13] = e[13] * h[13] + tu * b3.y;
        h[14] = e[14] * h[14] + tu * b3.z;  h[15] = e[15] * h[15] + tu * b3.w;
        float y = h[0]*c0.x + h[1]*c0.y + h[2]*c0.z + h[3]*c0.w
                + h[4]*c1.x + h[5]*c1.y + h[6]*c1.z + h[7]*c1.w
                + h[8]*c2.x + h[9]*c2.y + h[10]*c2.z + h[11]*c2.w
                + h[12]*c3.x + h[13]*c3.y + h[14]*c3.z + h[15]*c3.w;
        xs[l * XST + d] = y + Dval * u;
    }

    // packed bf16 chunk end-state
    size_t b8 = ((size_t)(k * NC + cc) * DD + d) * 8;
    uint4 p0, p1;
    p0.x = pk_bf2(h[0],  h[1]);  p0.y = pk_bf2(h[2],  h[3]);
    p0.z = pk_bf2(h[4],  h[5]);  p0.w = pk_bf2(h[6],  h[7]);
    p1.x = pk_bf2(h[8],  h[9]);  p1.y = pk_bf2(h[10], h[11]);
    p1.z = pk_bf2(h[12], h[13]); p1.w = pk_bf2(h[14], h[15]);
    *(uint4*)(S_b + b8)     = p0;
    *(uint4*)(S_b + b8 + 4) = p1;
    dtsum[(k * NC + cc) * DD + d] = dsum;
}

// ---------------------------------------------------------------------------
// K1: proj GEMM + phase A local scan. Block = (k, 32-l tile), 256 threads.
// ---------------------------------------------------------------------------
__global__ __launch_bounds__(256, 4) void k1_proj_scanA(
    const float* __restrict__ x, const float* __restrict__ Wp,
    const float* __restrict__ Wdt, const float* __restrict__ bias,
    const float* __restrict__ A_logs, const float* __restrict__ Ds,
    unsigned* __restrict__ S_b, float* __restrict__ dtsum,
    float* __restrict__ oy, float* __restrict__ csp,
    float* __restrict__ dsl)
{
    const int blk = blockIdx.x;
    const int k = blk >> 7;
    const int c = blk & 127;
    const int l0 = c * LB;
    const int t = threadIdx.x;

    __shared__ __align__(16) float xs[LB * XST];    // x-tile [l][d]; y overwrites
    __shared__ __align__(16) float sdbl[LB * SDST]; // x_dbl [l][c]
    __shared__ int pos_s[LB];

    if (t < LB) pos_s[t] = pos_of(k, l0 + t);
    __syncthreads();

    // ---- stage x tile (coalesced) ----
    {
        int lane32 = t & 31, rowi = t >> 5;
        #pragma unroll
        for (int p = 0; p < 4; p++) {
            int l = p * 8 + rowi;
            float4 v = *(const float4*)(x + (size_t)pos_s[l] * DD + lane32 * 4);
            *(float4*)(&xs[l * XST + lane32 * 4]) = v;
        }
    }
    __syncthreads();

    // ---- projection GEMM: group cg (of 8) computes 5 of 40 channels ----
    {
        int l = t & 31, cg = t >> 5;
        float acc[5];
        #pragma unroll
        for (int j = 0; j < 5; j++) acc[j] = 0.0f;
        const float* wk = Wp + (size_t)(k * 40 + cg * 5) * DD;
        for (int d4 = 0; d4 < DD; d4 += 4) {
            float4 xv = *(const float4*)(&xs[l * XST + d4]);
            #pragma unroll
            for (int j = 0; j < 5; j++) {
                const float* w = wk + j * DD + d4;   // wave-uniform -> s_load
                acc[j] += xv.x * w[0] + xv.y * w[1] + xv.z * w[2] + xv.w * w[3];
            }
        }
        #pragma unroll
        for (int j = 0; j < 5; j++) sdbl[l * SDST + cg * 5 + j] = acc[j];
    }
    __syncthreads();

    // ---- spill C columns only (32 l x 16 n) for K3 ----
    {
        float4* g4 = (float4*)(csp + (size_t)blk * 512);
        for (int idx = t; idx < 128; idx += 256) {
            int l = idx >> 2, q = idx & 3;
            g4[idx] = *(const float4*)(&sdbl[l * SDST + 24 + q * 4]);
        }
    }

    // ---- phase A scan: thread = (d, l-half) ----
    const int d = t & 127, half = t >> 7;
    const int cc = 2 * c + half, lbase = half * LCS;
    float A16[16];
    bool structured = load_A16(A_logs, k, d, A16);
    const float4* wp4 = (const float4*)(Wdt + (size_t)(k * DD + d) * RR);
    const float4 w0 = wp4[0], w1 = wp4[1];
    const float bz = bias[k * DD + d];
    const float Dval = Ds[k * DD + d];
    float* dslp = dsl + ((size_t)(k * LL + l0 + lbase)) * DD + d;

    if (structured)
        scanA_body<true>(xs, sdbl, k, cc, lbase, d, A16, w0, w1, bz, Dval,
                         S_b, dtsum, dslp);
    else
        scanA_body<false>(xs, sdbl, k, cc, lbase, d, A16, w0, w1, bz, Dval,
                          S_b, dtsum, dslp);

    // ---- transposed y store (self-written slots only; no barrier) ----
    {
        float* base = oy + ((size_t)(k * DD + d)) * LL + l0 + lbase;
        #pragma unroll
        for (int p = 0; p < 4; p++) {
            int j = p * 4;
            float4 v = make_float4(xs[(lbase + j + 0) * XST + d],
                                   xs[(lbase + j + 1) * XST + d],
                                   xs[(lbase + j + 2) * XST + d],
                                   xs[(lbase + j + 3) * XST + d]);
            *(float4*)(base + j) = v;
        }
    }
}

// ---------------------------------------------------------------------------
// K2: sequential combine across 256 sub-chunks; thread owns an n-pair so the
// packed bf16 uint is single-owner. S_b <- true h0, in place.
// ---------------------------------------------------------------------------
__global__ __launch_bounds__(256) void k2_combine(
    unsigned* __restrict__ S_b, const float* __restrict__ dtsum,
    const float* __restrict__ A_logs)
{
    int tid = blockIdx.x * 256 + threadIdx.x;   // k*1024 + d*8 + j(pair)
    int kk = tid >> 10, rem = tid & 1023, dd2 = rem >> 3, j = rem & 7;
    const float* ap = A_logs + ((size_t)kk * DD + dd2) * NN + 2 * j;
    float A0 = -__expf(ap[0]), A1 = -__expf(ap[1]);
    float h0 = 0.0f, h1 = 0.0f;
    #pragma unroll 8
    for (int c2 = 0; c2 < NC; c2++) {
        size_t b8 = ((size_t)(kk * NC + c2) * DD + dd2) * 8 + j;
        unsigned u = S_b[b8];
        float dsv = dtsum[(kk * NC + c2) * DD + dd2];
        float s0 = lo_bf(u), s1 = hi_bf(u);
        S_b[b8] = pk_bf2(h0, h1);
        h0 = s0 + __expf(dsv * A0) * h0;
        h1 = s1 + __expf(dsv * A1) * h1;
    }
}

// ---------------------------------------------------------------------------
// K3: correction, fully parallel (no serial deps, no dt recompute):
// y_corr(l) = sum_n C[n,l] * exp(Dsum_l * A[n]) * h0[n]; Dsum from dsl[k][l][d]
// (coalesced), C from csp via LDS (broadcast), h0 from S_b.
// ---------------------------------------------------------------------------
template<bool S>
__device__ __forceinline__ void corr_body(
    float* ybuf, const float* csp_s, const float* dslp, int lbase, int d,
    const float* A16, const float* g)
{
    #pragma unroll 4
    for (int i = 0; i < LCS; i++) {
        int l = lbase + i;
        float Dsum = dslp[(size_t)i * DD];    // coalesced 256B wave load
        float e[16];
        e16_from<S>(Dsum, A16, e);
        const float4* cp = (const float4*)(&csp_s[l * 16]);
        float4 c0 = cp[0], c1 = cp[1], c2 = cp[2], c3 = cp[3];
        float y = e[0]*g[0]*c0.x + e[1]*g[1]*c0.y + e[2]*g[2]*c0.z + e[3]*g[3]*c0.w
                + e[4]*g[4]*c1.x + e[5]*g[5]*c1.y + e[6]*g[6]*c1.z + e[7]*g[7]*c1.w
                + e[8]*g[8]*c2.x + e[9]*g[9]*c2.y + e[10]*g[10]*c2.z + e[11]*g[11]*c2.w
                + e[12]*g[12]*c3.x + e[13]*g[13]*c3.y + e[14]*g[14]*c3.z + e[15]*g[15]*c3.w;
        ybuf[l * XST + d] = y;
    }
}

__global__ __launch_bounds__(256, 4) void k3_corr(
    const float* __restrict__ A_logs, const unsigned* __restrict__ S_b,
    const float* __restrict__ csp, const float* __restrict__ dsl,
    float* __restrict__ oy)
{
    const int blk = blockIdx.x;
    const int k = blk >> 7;
    const int c = blk & 127;
    const int l0 = c * LB;
    const int t = threadIdx.x;

    __shared__ __align__(16) float csp_s[LB * 16];
    __shared__ __align__(16) float ybuf[LB * XST];
    {
        const float4* g4 = (const float4*)(csp + (size_t)blk * 512);
        float4* s4 = (float4*)csp_s;
        for (int idx = t; idx < 128; idx += 256) s4[idx] = g4[idx];
    }
    __syncthreads();

    const int d = t & 127, half = t >> 7;
    const int cc = 2 * c + half, lbase = half * LCS;
    float A16[16];
    bool structured = load_A16(A_logs, k, d, A16);
    const float* dslp = dsl + ((size_t)(k * LL + l0 + lbase)) * DD + d;

    float g[16];
    {
        const uint4* hp = (const uint4*)(S_b + ((size_t)(k * NC + cc) * DD + d) * 8);
        uint4 a = hp[0], b = hp[1];
        g[0]  = lo_bf(a.x); g[1]  = hi_bf(a.x); g[2]  = lo_bf(a.y); g[3]  = hi_bf(a.y);
        g[4]  = lo_bf(a.z); g[5]  = hi_bf(a.z); g[6]  = lo_bf(a.w); g[7]  = hi_bf(a.w);
        g[8]  = lo_bf(b.x); g[9]  = hi_bf(b.x); g[10] = lo_bf(b.y); g[11] = hi_bf(b.y);
        g[12] = lo_bf(b.z); g[13] = hi_bf(b.z); g[14] = lo_bf(b.w); g[15] = hi_bf(b.w);
    }

    if (structured)
        corr_body<true>(ybuf, csp_s, dslp, lbase, d, A16, g);
    else
        corr_body<false>(ybuf, csp_s, dslp, lbase, d, A16, g);

    // ---- transposed RMW of oy tile (self-written slots only) ----
    {
        float* base = oy + ((size_t)(k * DD + d)) * LL + l0 + lbase;
        #pragma unroll
        for (int p = 0; p < 4; p++) {
            int j = p * 4;
            float4 v = *(float4*)(base + j);
            v.x += ybuf[(lbase + j + 0) * XST + d];
            v.y += ybuf[(lbase + j + 1) * XST + d];
            v.z += ybuf[(lbase + j + 2) * XST + d];
            v.w += ybuf[(lbase + j + 3) * XST + d];
            *(float4*)(base + j) = v;
        }
    }
}

// ---------------------------------------------------------------------------
// K4: restore + merge (reference's (D,L)-flat reshape semantics).
// ---------------------------------------------------------------------------
__global__ __launch_bounds__(256) void k4_merge(
    const float* __restrict__ out_y, const float* __restrict__ mw,
    const float* __restrict__ mb, float* __restrict__ out)
{
    int idx = blockIdx.x * 256 + threadIdx.x;
    int dd = idx & 127;
    int p = idx >> 7;
    int i3 = p & 15, i2 = (p >> 4) & 15, i1 = (p >> 8) & 15;

    float accv = mb[0];
    #pragma unroll
    for (int k = 0; k < 12; k++) {
        int a1 = i1, a2 = i2, a3 = i3;
        if (k & 1) { a1 = 15 - i1; a2 = 15 - i2; a3 = 15 - i3; }
        int j1, j2, j3;
        switch (k >> 1) {
            case 0:  j1 = a1; j2 = a2; j3 = a3; break;
            case 1:  j1 = a1; j2 = a3; j3 = a2; break;
            case 2:  j1 = a3; j2 = a2; j3 = a1; break;
            case 3:  j1 = a3; j2 = a1; j3 = a2; break;
            case 4:  j1 = a2; j2 = a1; j3 = a3; break;
            default: j1 = a2; j2 = a3; j3 = a1; break;
        }
        int jb = (j1 << 8) | (j2 << 4) | j3;
        accv += mw[k] * out_y[(size_t)k * (DD * LL) + (jb >> 5) * LL
                              + ((jb & 31) << 7) + dd];
    }
    out[idx] = accv;
}

extern "C" void kernel_launch(void* const* d_in, const int* in_sizes, int n_in,
                              void* d_out, int out_size, void* d_ws, size_t ws_size,
                              hipStream_t stream) {
    const float* x      = (const float*)d_in[0];
    const float* Wp     = (const float*)d_in[1];
    const float* Wdt    = (const float*)d_in[2];
    const float* bias   = (const float*)d_in[3];
    const float* A_logs = (const float*)d_in[4];
    const float* Ds     = (const float*)d_in[5];
    const float* mw     = (const float*)d_in[6];
    const float* mb     = (const float*)d_in[7];
    float* out = (float*)d_out;

    // workspace: ~67.6 MB total
    unsigned* S_b = (unsigned*)d_ws;                    // K*NC*D*8 uints = 3145728
    float* dts  = (float*)(S_b + (size_t)KK * NC * DD * 8); // K*NC*D    =  393216
    float* oy   = dts + (size_t)KK * NC * DD;           // K*D*L       = 6291456
    float* csp  = oy + (size_t)KK * DD * LL;            // 1536*512    =  786432
    float* dsl  = csp + (size_t)KK * 128 * 512;         // K*L*D       = 6291456

    k1_proj_scanA<<<dim3(KK * 128), dim3(256), 0, stream>>>(
        x, Wp, Wdt, bias, A_logs, Ds, S_b, dts, oy, csp, dsl);
    k2_combine<<<dim3(KK * DD * 8 / 256), dim3(256), 0, stream>>>(S_b, dts, A_logs);
    k3_corr<<<dim3(KK * 128), dim3(256), 0, stream>>>(A_logs, S_b, csp, dsl, oy);
    k4_merge<<<dim3(LL * DD / 256), dim3(256), 0, stream>>>(oy, mw, mb, out);
}